// Round 11
// baseline (91.600 us; speedup 1.0000x reference)
//
#include <hip/hip_runtime.h>
#include <math.h>

#define N_ROWS 32768
#define DIM    256
#define KC     1024
#define BM     64
#define BN     64
#define DSTEP  32
#define PAD_M  68

typedef unsigned short u16;
typedef __attribute__((ext_vector_type(8))) short short8;
typedef __attribute__((ext_vector_type(4))) float f32x4;

__device__ __forceinline__ u16 bf16_rne(float f) {
    unsigned u = __float_as_uint(f);
    return (u16)((u + 0x7fffu + ((u >> 16) & 1u)) >> 16);
}

// ---------------- split codebook f32 -> bf16, fused row norms + hist zero ----------
__global__ __launch_bounds__(256) void split_e_kernel(const float* __restrict__ emb,
                                                      u16* __restrict__ hi,
                                                      float* __restrict__ enorm,
                                                      int* __restrict__ hist) {
    if (blockIdx.x < 4) hist[blockIdx.x * 256 + threadIdx.x] = 0;
    const int lane = threadIdx.x & 63;
    const int row  = blockIdx.x * 4 + (threadIdx.x >> 6);
    float4 v = ((const float4*)(emb + (size_t)row * DIM))[lane];
    ushort4 hv;
    hv.x = bf16_rne(v.x); hv.y = bf16_rne(v.y);
    hv.z = bf16_rne(v.z); hv.w = bf16_rne(v.w);
    ((ushort4*)(hi + (size_t)row * DIM))[lane] = hv;
    float ss = v.x * v.x + v.y * v.y + v.z * v.z + v.w * v.w;
    #pragma unroll
    for (int off = 32; off >= 1; off >>= 1) ss += __shfl_xor(ss, off);
    if (lane == 0) enorm[row] = ss;
}

// ---------------- fused argmin: A in swizzled LDS, B direct from L2, no loop barriers
// Block: 256 thr / 4 waves = 2 row-groups x 2 col-groups; 64 rows x 1024 cols.
// Grid 512 -> 2 blocks/CU (32 KB LDS), 16 waves/CU, all barrier-free in the K-loop:
// B fragments are per-lane 16B dwordx4 loads straight from the L2-resident codebook
// (r10 lesson: LDS-staged B cost 20 µs of ds_reads + 16 vmcnt(0) barrier drains;
// the compiler also refuses to hoist A across barrier loops - so remove the barriers
// and the B staging instead of fighting the register allocator).
__global__ __launch_bounds__(256) void fused_argmin_kernel(
        const float* __restrict__ lat, const u16* __restrict__ eh,
        const float* __restrict__ enorm,
        int* __restrict__ inds, int* __restrict__ hist,
        double* __restrict__ partials) {
    __shared__ u16    Atile[64 * 256];    // 32 KB, swizzled
    __shared__ float  xn_lds[64];
    __shared__ float  ep_b[64][2];
    __shared__ int    ep_i[64][2];
    __shared__ double sred[64];

    const int tid  = threadIdx.x;
    const int l    = tid & 63;
    const int w    = tid >> 6;      // 0..3
    const int wrow = w >> 1;        // 0..1 : row group (32 rows each)
    const int wc   = w & 1;         // 0..1 : col group (32 cols per 64-col chunk)
    const int lcol = l & 15;
    const int kseg = l >> 4;        // 0..3
    const size_t row0 = (size_t)blockIdx.x * 64;

    // ---- prologue: stage A (f32->bf16, swizzled) + per-row ||x||^2 ----
    #pragma unroll
    for (int i = 0; i < 8; ++i) {
        const int p   = i * 256 + tid;   // 0..2047 = 64 rows x 32 chunks
        const int row = p >> 5;
        const int chl = p & 31;
        const float* src = lat + (row0 + row) * 256 + chl * 8;
        float4 v0 = *(const float4*)src;
        float4 v1 = *(const float4*)(src + 4);
        short8 d;
        d[0] = (short)bf16_rne(v0.x); d[1] = (short)bf16_rne(v0.y);
        d[2] = (short)bf16_rne(v0.z); d[3] = (short)bf16_rne(v0.w);
        d[4] = (short)bf16_rne(v1.x); d[5] = (short)bf16_rne(v1.y);
        d[6] = (short)bf16_rne(v1.z); d[7] = (short)bf16_rne(v1.w);
        *(short8*)&Atile[(row * 32 + (chl ^ (row & 7))) * 8] = d;
        // row-norm: 32 consecutive threads (one 32-lane group) share a row
        float ss = v0.x * v0.x + v0.y * v0.y + v0.z * v0.z + v0.w * v0.w
                 + v1.x * v1.x + v1.y * v1.y + v1.z * v1.z + v1.w * v1.w;
        ss += __shfl_xor(ss, 1);  ss += __shfl_xor(ss, 2);
        ss += __shfl_xor(ss, 4);  ss += __shfl_xor(ss, 8);
        ss += __shfl_xor(ss, 16);
        if ((tid & 31) == 0) xn_lds[row] = ss;   // unique writer per row
    }
    __syncthreads();   // the ONLY staging barrier

    // ---- A fragments (re-read from LDS by the compiler if it wants; conflict-free)
    short8 afr[2][8];
    #pragma unroll
    for (int mf = 0; mf < 2; ++mf) {
        const int ra = wrow * 32 + mf * 16 + lcol;
        #pragma unroll
        for (int ks = 0; ks < 8; ++ks) {
            const int ch = ks * 4 + kseg;
            afr[mf][ks] = *(const short8*)&Atile[(ra * 32 + (ch ^ (ra & 7))) * 8];
        }
    }

    float best[2][4];
    int   bidx[2][4];
    #pragma unroll
    for (int mf = 0; mf < 2; ++mf)
        #pragma unroll
        for (int r = 0; r < 4; ++r) { best[mf][r] = INFINITY; bidx[mf][r] = 0; }

    const int rb0 = wc * 32 + lcol;      // nf = 0 column (within 64-col chunk)
    const int rb1 = rb0 + 16;            // nf = 1
    for (int c = 0; c < 16; ++c) {
        const float en0 = enorm[c * 64 + rb0];
        const float en1 = enorm[c * 64 + rb1];
        const u16* bp0 = eh + (size_t)(c * 64 + rb0) * 256 + kseg * 8;
        const u16* bp1 = eh + (size_t)(c * 64 + rb1) * 256 + kseg * 8;

        f32x4 acc[2][2];
        #pragma unroll
        for (int mf = 0; mf < 2; ++mf)
            #pragma unroll
            for (int nf = 0; nf < 2; ++nf)
                acc[mf][nf] = (f32x4){0.f, 0.f, 0.f, 0.f};

        #pragma unroll
        for (int ks = 0; ks < 8; ++ks) {
            short8 b0 = *(const short8*)(bp0 + ks * 32);   // k-range ks*32+kseg*8
            short8 b1 = *(const short8*)(bp1 + ks * 32);
            #pragma unroll
            for (int mf = 0; mf < 2; ++mf) {
                acc[mf][0] = __builtin_amdgcn_mfma_f32_16x16x32_bf16(
                    afr[mf][ks], b0, acc[mf][0], 0, 0, 0);
                acc[mf][1] = __builtin_amdgcn_mfma_f32_16x16x32_bf16(
                    afr[mf][ks], b1, acc[mf][1], 0, 0, 0);
            }
        }

        const int col0 = c * 64 + rb0;
        const int col1 = c * 64 + rb1;
        #pragma unroll
        for (int mf = 0; mf < 2; ++mf)
            #pragma unroll
            for (int r = 0; r < 4; ++r) {
                float d0 = fmaf(-2.f, acc[mf][0][r], en0);
                if (d0 < best[mf][r]) { best[mf][r] = d0; bidx[mf][r] = col0; }
                float d1 = fmaf(-2.f, acc[mf][1][r], en1);
                if (d1 < best[mf][r]) { best[mf][r] = d1; bidx[mf][r] = col1; }
            }
    }

    // merge across the 16-lane col group (tie-break: smallest index)
    #pragma unroll
    for (int m = 1; m < 16; m <<= 1) {
        #pragma unroll
        for (int mf = 0; mf < 2; ++mf)
            #pragma unroll
            for (int r = 0; r < 4; ++r) {
                float b2 = __shfl_xor(best[mf][r], m);
                int   i2 = __shfl_xor(bidx[mf][r], m);
                if (b2 < best[mf][r] || (b2 == best[mf][r] && i2 < bidx[mf][r])) {
                    best[mf][r] = b2; bidx[mf][r] = i2;
                }
            }
    }
    if (lcol == 0) {
        #pragma unroll
        for (int mf = 0; mf < 2; ++mf)
            #pragma unroll
            for (int r = 0; r < 4; ++r) {
                const int rr = wrow * 32 + mf * 16 + kseg * 4 + r;
                ep_b[rr][wc] = best[mf][r];
                ep_i[rr][wc] = bidx[mf][r];
            }
    }
    __syncthreads();

    // final per-row merge; dist = ||x||^2 + best(enorm - 2 dot)
    if (tid < 64) {
        float b = ep_b[tid][0]; int bi = ep_i[tid][0];
        float b2 = ep_b[tid][1]; int i2 = ep_i[tid][1];
        if (b2 < b || (b2 == b && i2 < bi)) { b = b2; bi = i2; }
        inds[row0 + tid] = bi;
        atomicAdd(&hist[bi], 1);
        sred[tid] = (double)xn_lds[tid] + (double)b;
    }
    __syncthreads();
    for (int st = 32; st >= 1; st >>= 1) {
        if (tid < st) sred[tid] += sred[tid + st];
        __syncthreads();
    }
    if (tid == 0) partials[blockIdx.x] = sred[0];
}

// ---------------- write quantized output ----------------
__global__ __launch_bounds__(256) void writeq_kernel(const float* __restrict__ emb,
                                                     const int* __restrict__ inds,
                                                     float* __restrict__ out) {
    const int nvec = N_ROWS * DIM / 4;
    for (int idx = blockIdx.x * 256 + threadIdx.x; idx < nvec;
         idx += gridDim.x * 256) {
        int row = idx >> 6;
        int dv  = idx & 63;
        int k   = inds[row];
        ((float4*)out)[idx] = ((const float4*)(emb + (size_t)k * DIM))[dv];
    }
}

// ---------------- finalize: vq_loss + perplexity ----------------
__global__ __launch_bounds__(256) void finalize_kernel(const int* __restrict__ hist,
                                                       const double* __restrict__ partials,
                                                       int np,
                                                       float* __restrict__ out_tail) {
    __shared__ double sh[256];
    const int tid = threadIdx.x;
    double s = 0.0;
    for (int i = tid; i < np; i += 256) s += partials[i];
    sh[tid] = s; __syncthreads();
    for (int st = 128; st > 0; st >>= 1) {
        if (tid < st) sh[tid] += sh[tid + st];
        __syncthreads();
    }
    double sumsq = sh[0];
    __syncthreads();
    double e = 0.0;
    for (int k = tid; k < KC; k += 256) {
        double p = (double)hist[k] / (double)N_ROWS;
        e += p * log(p + 1e-10);
    }
    sh[tid] = e; __syncthreads();
    for (int st = 128; st > 0; st >>= 1) {
        if (tid < st) sh[tid] += sh[tid + st];
        __syncthreads();
    }
    if (tid == 0) {
        double mse = sumsq / (double)((size_t)N_ROWS * DIM);
        out_tail[0] = (float)(1.25 * mse);
        out_tail[1] = (float)exp(-sh[0]);
    }
}

// ================= fallback path (ws too small) =================
__global__ __launch_bounds__(256) void enorm_kernel(const float* __restrict__ emb,
                                                    float* __restrict__ enorm) {
    int k = blockIdx.x * blockDim.x + threadIdx.x;
    if (k >= KC) return;
    const float4* row = (const float4*)(emb + (size_t)k * DIM);
    float s = 0.f;
    #pragma unroll 4
    for (int i = 0; i < DIM / 4; ++i) {
        float4 v = row[i];
        s += v.x * v.x + v.y * v.y + v.z * v.z + v.w * v.w;
    }
    enorm[k] = s;
}

__global__ __launch_bounds__(256) void argmin_kernel(const float* __restrict__ lat,
                                                     const float* __restrict__ emb,
                                                     const float* __restrict__ enorm,
                                                     int* __restrict__ inds,
                                                     int* __restrict__ hist) {
    __shared__ float As[DSTEP][PAD_M];
    __shared__ float Bs[DSTEP][PAD_M];
    __shared__ float rbest[BM][17];
    __shared__ int   ridx[BM][17];

    const int tid = threadIdx.x;
    const int tx = tid & 15;
    const int ty = tid >> 4;
    const int row0 = blockIdx.x * BM;
    const int lm  = tid >> 2;
    const int ld0 = (tid & 3) * 8;

    float best[4];
    int bidx[4];
    #pragma unroll
    for (int i = 0; i < 4; ++i) { best[i] = INFINITY; bidx[i] = 0; }

    for (int ct = 0; ct < KC / BN; ++ct) {
        float acc[4][4];
        #pragma unroll
        for (int i = 0; i < 4; ++i)
            #pragma unroll
            for (int j = 0; j < 4; ++j) acc[i][j] = 0.f;

        for (int dc = 0; dc < DIM; dc += DSTEP) {
            const float* ap = lat + (size_t)(row0 + lm) * DIM + dc + ld0;
            float4 a0 = *(const float4*)ap;
            float4 a1 = *(const float4*)(ap + 4);
            As[ld0 + 0][lm] = a0.x; As[ld0 + 1][lm] = a0.y;
            As[ld0 + 2][lm] = a0.z; As[ld0 + 3][lm] = a0.w;
            As[ld0 + 4][lm] = a1.x; As[ld0 + 5][lm] = a1.y;
            As[ld0 + 6][lm] = a1.z; As[ld0 + 7][lm] = a1.w;
            const float* bp = emb + (size_t)(ct * BN + lm) * DIM + dc + ld0;
            float4 b0 = *(const float4*)bp;
            float4 b1 = *(const float4*)(bp + 4);
            Bs[ld0 + 0][lm] = b0.x; Bs[ld0 + 1][lm] = b0.y;
            Bs[ld0 + 2][lm] = b0.z; Bs[ld0 + 3][lm] = b0.w;
            Bs[ld0 + 4][lm] = b1.x; Bs[ld0 + 5][lm] = b1.y;
            Bs[ld0 + 6][lm] = b1.z; Bs[ld0 + 7][lm] = b1.w;
            __syncthreads();
            #pragma unroll
            for (int d = 0; d < DSTEP; ++d) {
                float4 av = *(const float4*)&As[d][ty * 4];
                float4 bv = *(const float4*)&Bs[d][tx * 4];
                float a[4] = {av.x, av.y, av.z, av.w};
                float b[4] = {bv.x, bv.y, bv.z, bv.w};
                #pragma unroll
                for (int i = 0; i < 4; ++i)
                    #pragma unroll
                    for (int j = 0; j < 4; ++j)
                        acc[i][j] = fmaf(a[i], b[j], acc[i][j]);
            }
            __syncthreads();
        }
        #pragma unroll
        for (int j = 0; j < 4; ++j) {
            int n = ct * BN + tx * 4 + j;
            float en = enorm[n];
            #pragma unroll
            for (int i = 0; i < 4; ++i) {
                float dist = fmaf(-2.f, acc[i][j], en);
                if (dist < best[i]) { best[i] = dist; bidx[i] = n; }
            }
        }
    }
    #pragma unroll
    for (int i = 0; i < 4; ++i) {
        rbest[ty * 4 + i][tx] = best[i];
        ridx [ty * 4 + i][tx] = bidx[i];
    }
    __syncthreads();
    if (tid < BM) {
        float g1 = INFINITY;
        int i1 = 0x7fffffff;
        for (int t = 0; t < 16; ++t) {
            float d = rbest[tid][t];
            int   ix = ridx[tid][t];
            if (d < g1 || (d == g1 && ix < i1)) { g1 = d; i1 = ix; }
        }
        inds[row0 + tid] = i1;
        atomicAdd(&hist[i1], 1);
    }
}

__global__ __launch_bounds__(256) void gather_kernel(const float* __restrict__ lat,
                                                     const float* __restrict__ emb,
                                                     const int* __restrict__ inds,
                                                     float* __restrict__ out,
                                                     double* __restrict__ partials) {
    __shared__ double wsum[4];
    const int tid = threadIdx.x;
    double acc = 0.0;
    const int nvec = N_ROWS * DIM / 4;
    for (int idx = blockIdx.x * blockDim.x + tid; idx < nvec; idx += gridDim.x * blockDim.x) {
        int row = idx >> 6;
        int dv = idx & 63;
        int k = inds[row];
        float4 xv = ((const float4*)lat)[idx];
        float4 qv = ((const float4*)(emb + (size_t)k * DIM))[dv];
        float d0 = qv.x - xv.x, d1 = qv.y - xv.y, d2 = qv.z - xv.z, d3 = qv.w - xv.w;
        float4 o;
        o.x = xv.x + d0; o.y = xv.y + d1; o.z = xv.z + d2; o.w = xv.w + d3;
        ((float4*)out)[idx] = o;
        acc += (double)d0 * d0 + (double)d1 * d1 + (double)d2 * d2 + (double)d3 * d3;
    }
    #pragma unroll
    for (int off = 32; off >= 1; off >>= 1) acc += __shfl_xor(acc, off);
    if ((tid & 63) == 0) wsum[tid >> 6] = acc;
    __syncthreads();
    if (tid == 0) partials[blockIdx.x] = wsum[0] + wsum[1] + wsum[2] + wsum[3];
}

extern "C" void kernel_launch(void* const* d_in, const int* in_sizes, int n_in,
                              void* d_out, int out_size, void* d_ws, size_t ws_size,
                              hipStream_t stream) {
    const float* lat = (const float*)d_in[0];
    const float* emb = (const float*)d_in[1];
    float* out = (float*)d_out;

    char* ws = (char*)d_ws;
    int*    hist     = (int*)(ws);                    // 4 KB
    float*  enorm    = (float*)(ws + 4096);           // 4 KB
    int*    inds     = (int*)(ws + 8192);             // 128 KB
    double* partials = (double*)(ws + 139264);        // 16 KB (512 used)
    u16*    eh       = (u16*)(ws + 155648);           // 512 KB
    const size_t WS_NEED = 155648 + 524288;

    if (ws_size >= WS_NEED) {
        split_e_kernel<<<KC / 4, 256, 0, stream>>>(emb, eh, enorm, hist);
        fused_argmin_kernel<<<N_ROWS / 64, 256, 0, stream>>>(lat, eh, enorm,
                                                             inds, hist, partials);
        writeq_kernel<<<2048, 256, 0, stream>>>(emb, inds, out);
        finalize_kernel<<<1, 256, 0, stream>>>(hist, partials, N_ROWS / 64,
                                               out + (size_t)N_ROWS * DIM);
    } else {
        hipMemsetAsync(hist, 0, KC * sizeof(int), stream);
        enorm_kernel<<<KC / 256, 256, 0, stream>>>(emb, enorm);
        argmin_kernel<<<N_ROWS / BM, 256, 0, stream>>>(lat, emb, enorm, inds, hist);
        gather_kernel<<<2048, 256, 0, stream>>>(lat, emb, inds, out, partials);
        finalize_kernel<<<1, 256, 0, stream>>>(hist, partials, 2048,
                                               out + (size_t)N_ROWS * DIM);
    }
}

// Round 12
// 60.689 us; speedup vs baseline: 1.5093x; 1.5093x over previous
//
#include <hip/hip_runtime.h>
#include <math.h>

#define N_ROWS 32768
#define DIM    256
#define KC     1024
#define BM     64
#define BN     64
#define DSTEP  32
#define PAD_M  68

typedef unsigned short u16;
typedef __attribute__((ext_vector_type(8))) short short8;
typedef __attribute__((ext_vector_type(4))) float f32x4;

__device__ __forceinline__ u16 bf16_rne(float f) {
    unsigned u = __float_as_uint(f);
    return (u16)((u + 0x7fffu + ((u >> 16) & 1u)) >> 16);
}

// ---------------- split codebook f32 -> bf16, fused row norms + hist zero ----------
__global__ __launch_bounds__(256) void split_e_kernel(const float* __restrict__ emb,
                                                      u16* __restrict__ hi,
                                                      float* __restrict__ enorm,
                                                      int* __restrict__ hist) {
    if (blockIdx.x < 4) hist[blockIdx.x * 256 + threadIdx.x] = 0;
    const int lane = threadIdx.x & 63;
    const int row  = blockIdx.x * 4 + (threadIdx.x >> 6);
    float4 v = ((const float4*)(emb + (size_t)row * DIM))[lane];
    ushort4 hv;
    hv.x = bf16_rne(v.x); hv.y = bf16_rne(v.y);
    hv.z = bf16_rne(v.z); hv.w = bf16_rne(v.w);
    ((ushort4*)(hi + (size_t)row * DIM))[lane] = hv;
    float ss = v.x * v.x + v.y * v.y + v.z * v.z + v.w * v.w;
    #pragma unroll
    for (int off = 32; off >= 1; off >>= 1) ss += __shfl_xor(ss, off);
    if (lane == 0) enorm[row] = ss;
}

// ---------------- fused argmin + quantized write (r10 skeleton + counted vmcnt) ----
// Block: 512 thr / 8 waves = 4 row-groups x 2 col-groups; 128 rows x 1024 cols.
// A staged once into swizzled LDS (f32->bf16); B double-buffered 64-col chunks via
// global_load_lds (pre-swizzled source). T4: raw s_barrier pairs with counted
// s_waitcnt vmcnt(4) keep the next chunk's 4 loads IN FLIGHT across the barrier
// (HIP __syncthreads would drain vmcnt(0) every chunk). enorm staged to LDS so the
// loop's ONLY vmcnt ops are the 4 prefetches (a stray global load would force the
// compiler to auto-drain). Quantized-output gather fused into the tail.
__global__ __launch_bounds__(512) void fused_argmin_kernel(
        const float* __restrict__ lat, const float* __restrict__ emb,
        const u16* __restrict__ eh, const float* __restrict__ enorm,
        int* __restrict__ inds, int* __restrict__ hist,
        double* __restrict__ partials, float* __restrict__ out) {
    __shared__ u16    Atile[128 * 256];   // 64 KB, swizzled
    __shared__ u16    Bbuf[2][64 * 256];  // 2 x 32 KB, swizzled (via src)
    __shared__ float  en_lds[KC];         // 4 KB
    __shared__ float  xn_lds[128];
    __shared__ float  ep_b[128][2];
    __shared__ int    ep_i[128][2];
    __shared__ double sred[128];

    const int tid  = threadIdx.x;
    const int l    = tid & 63;
    const int w    = tid >> 6;
    const int wrow = w >> 1;        // 0..3 : row group (32 rows each)
    const int wc   = w & 1;         // 0..1 : col group (32 cols per 64-col chunk)
    const int lcol = l & 15;
    const int kseg = l >> 4;        // 0..3
    const size_t row0 = (size_t)blockIdx.x * 128;

    // ---- prologue: stage A (f32->bf16, swizzled) + ||x||^2 + enorm -> LDS ----
    en_lds[tid] = enorm[tid];
    en_lds[tid + 512] = enorm[tid + 512];
    #pragma unroll
    for (int i = 0; i < 8; ++i) {
        const int p   = i * 512 + tid;   // 0..4095 = 128 rows x 32 chunks
        const int row = p >> 5;
        const int chl = p & 31;
        const float* src = lat + (row0 + row) * 256 + chl * 8;
        float4 v0 = *(const float4*)src;
        float4 v1 = *(const float4*)(src + 4);
        short8 d;
        d[0] = (short)bf16_rne(v0.x); d[1] = (short)bf16_rne(v0.y);
        d[2] = (short)bf16_rne(v0.z); d[3] = (short)bf16_rne(v0.w);
        d[4] = (short)bf16_rne(v1.x); d[5] = (short)bf16_rne(v1.y);
        d[6] = (short)bf16_rne(v1.z); d[7] = (short)bf16_rne(v1.w);
        *(short8*)&Atile[(row * 32 + (chl ^ (row & 7))) * 8] = d;
        float ss = v0.x * v0.x + v0.y * v0.y + v0.z * v0.z + v0.w * v0.w
                 + v1.x * v1.x + v1.y * v1.y + v1.z * v1.z + v1.w * v1.w;
        ss += __shfl_xor(ss, 1);  ss += __shfl_xor(ss, 2);
        ss += __shfl_xor(ss, 4);  ss += __shfl_xor(ss, 8);
        ss += __shfl_xor(ss, 16);
        if ((tid & 31) == 0) xn_lds[row] = ss;
    }
    // issue B chunk 0 (pre-swizzled global source, linear LDS dest)
    #pragma unroll
    for (int i = 0; i < 4; ++i) {
        const int p = i * 512 + tid;     // 0..2047 = 64 rows x 32 chunks
        const int row = p >> 5;
        const int chp = p & 31;
        const u16* gb = eh + (size_t)row * 256 + (chp ^ (row & 7)) * 8;
        __builtin_amdgcn_global_load_lds(
            (const __attribute__((address_space(1))) void*)gb,
            (__attribute__((address_space(3))) void*)&Bbuf[0][p * 8], 16, 0, 0);
    }
    __syncthreads();   // staging barrier: drains A ds_writes AND chunk-0 loads

    float best[2][4];
    int   bidx[2][4];
    #pragma unroll
    for (int mf = 0; mf < 2; ++mf)
        #pragma unroll
        for (int r = 0; r < 4; ++r) { best[mf][r] = INFINITY; bidx[mf][r] = 0; }

    const int rb0 = wc * 32 + lcol;      // nf = 0 column (within 64-col chunk)
    const int rb1 = rb0 + 16;            // nf = 1
    for (int c = 0; c < 16; ++c) {
        if (c < 15) {   // prefetch next chunk into the other buffer
            #pragma unroll
            for (int i = 0; i < 4; ++i) {
                const int p = i * 512 + tid;
                const int row = p >> 5;
                const int chp = p & 31;
                const u16* gb = eh + (size_t)((c + 1) * 64 + row) * 256
                                   + (chp ^ (row & 7)) * 8;
                __builtin_amdgcn_global_load_lds(
                    (const __attribute__((address_space(1))) void*)gb,
                    (__attribute__((address_space(3))) void*)&Bbuf[(c + 1) & 1][p * 8],
                    16, 0, 0);
            }
            asm volatile("s_waitcnt vmcnt(4)" ::: "memory");  // chunk-c loads done; c+1 in flight
        } else {
            asm volatile("s_waitcnt vmcnt(0)" ::: "memory");  // last chunk: drain
        }
        __builtin_amdgcn_sched_barrier(0);
        __builtin_amdgcn_s_barrier();    // all threads' chunk-c loads landed
        __builtin_amdgcn_sched_barrier(0);

        const u16* Bb = Bbuf[c & 1];
        const float en0 = en_lds[c * 64 + rb0];
        const float en1 = en_lds[c * 64 + rb1];

        f32x4 acc[2][2];
        #pragma unroll
        for (int mf = 0; mf < 2; ++mf)
            #pragma unroll
            for (int nf = 0; nf < 2; ++nf)
                acc[mf][nf] = (f32x4){0.f, 0.f, 0.f, 0.f};

        #pragma unroll
        for (int ks = 0; ks < 8; ++ks) {
            const int ch = ks * 4 + kseg;
            short8 b0 = *(const short8*)&Bb[(rb0 * 32 + (ch ^ (rb0 & 7))) * 8];
            short8 b1 = *(const short8*)&Bb[(rb1 * 32 + (ch ^ (rb1 & 7))) * 8];
            #pragma unroll
            for (int mf = 0; mf < 2; ++mf) {
                const int ra = wrow * 32 + mf * 16 + lcol;
                short8 a = *(const short8*)&Atile[(ra * 32 + (ch ^ (ra & 7))) * 8];
                acc[mf][0] = __builtin_amdgcn_mfma_f32_16x16x32_bf16(a, b0, acc[mf][0], 0, 0, 0);
                acc[mf][1] = __builtin_amdgcn_mfma_f32_16x16x32_bf16(a, b1, acc[mf][1], 0, 0, 0);
            }
        }

        const int col0 = c * 64 + rb0;
        const int col1 = c * 64 + rb1;
        #pragma unroll
        for (int mf = 0; mf < 2; ++mf)
            #pragma unroll
            for (int r = 0; r < 4; ++r) {
                float d0 = fmaf(-2.f, acc[mf][0][r], en0);
                if (d0 < best[mf][r]) { best[mf][r] = d0; bidx[mf][r] = col0; }
                float d1 = fmaf(-2.f, acc[mf][1][r], en1);
                if (d1 < best[mf][r]) { best[mf][r] = d1; bidx[mf][r] = col1; }
            }
        __builtin_amdgcn_sched_barrier(0);
        __builtin_amdgcn_s_barrier();    // Bbuf[c&1] reads done -> c+2 may overwrite
        __builtin_amdgcn_sched_barrier(0);
    }

    // merge across the 16-lane col group (tie-break: smallest index)
    #pragma unroll
    for (int m = 1; m < 16; m <<= 1) {
        #pragma unroll
        for (int mf = 0; mf < 2; ++mf)
            #pragma unroll
            for (int r = 0; r < 4; ++r) {
                float b2 = __shfl_xor(best[mf][r], m);
                int   i2 = __shfl_xor(bidx[mf][r], m);
                if (b2 < best[mf][r] || (b2 == best[mf][r] && i2 < bidx[mf][r])) {
                    best[mf][r] = b2; bidx[mf][r] = i2;
                }
            }
    }
    if (lcol == 0) {
        #pragma unroll
        for (int mf = 0; mf < 2; ++mf)
            #pragma unroll
            for (int r = 0; r < 4; ++r) {
                const int rr = wrow * 32 + mf * 16 + kseg * 4 + r;
                ep_b[rr][wc] = best[mf][r];
                ep_i[rr][wc] = bidx[mf][r];
            }
    }
    __syncthreads();

    // final per-row merge; dist = ||x||^2 + best(enorm - 2 dot); winner -> ep_i[r][0]
    if (tid < 128) {
        float b = ep_b[tid][0]; int bi = ep_i[tid][0];
        float b2 = ep_b[tid][1]; int i2 = ep_i[tid][1];
        if (b2 < b || (b2 == b && i2 < bi)) { b = b2; bi = i2; }
        inds[row0 + tid] = bi;
        atomicAdd(&hist[bi], 1);
        sred[tid] = (double)xn_lds[tid] + (double)b;
        ep_i[tid][0] = bi;
    }
    __syncthreads();

    // fused quantized-output write (emb rows are L2-resident; coalesced stores)
    #pragma unroll
    for (int i = 0; i < 16; ++i) {
        const int vec = i * 512 + tid;        // 0..8191 = 128 rows x 64 float4
        const int row = vec >> 6;
        const int dv  = vec & 63;
        const int k   = ep_i[row][0];
        ((float4*)out)[(row0 + row) * 64 + dv] =
            ((const float4*)emb)[(size_t)k * 64 + dv];
    }

    for (int st = 64; st >= 1; st >>= 1) {
        if (tid < st) sred[tid] += sred[tid + st];
        __syncthreads();
    }
    if (tid == 0) partials[blockIdx.x] = sred[0];
}

// ---------------- finalize: vq_loss + perplexity ----------------
__global__ __launch_bounds__(256) void finalize_kernel(const int* __restrict__ hist,
                                                       const double* __restrict__ partials,
                                                       int np,
                                                       float* __restrict__ out_tail) {
    __shared__ double sh[256];
    const int tid = threadIdx.x;
    double s = 0.0;
    for (int i = tid; i < np; i += 256) s += partials[i];
    sh[tid] = s; __syncthreads();
    for (int st = 128; st > 0; st >>= 1) {
        if (tid < st) sh[tid] += sh[tid + st];
        __syncthreads();
    }
    double sumsq = sh[0];
    __syncthreads();
    double e = 0.0;
    for (int k = tid; k < KC; k += 256) {
        double p = (double)hist[k] / (double)N_ROWS;
        e += p * log(p + 1e-10);
    }
    sh[tid] = e; __syncthreads();
    for (int st = 128; st > 0; st >>= 1) {
        if (tid < st) sh[tid] += sh[tid + st];
        __syncthreads();
    }
    if (tid == 0) {
        double mse = sumsq / (double)((size_t)N_ROWS * DIM);
        out_tail[0] = (float)(1.25 * mse);
        out_tail[1] = (float)exp(-sh[0]);
    }
}

// ================= fallback path (ws too small) =================
__global__ __launch_bounds__(256) void enorm_kernel(const float* __restrict__ emb,
                                                    float* __restrict__ enorm) {
    int k = blockIdx.x * blockDim.x + threadIdx.x;
    if (k >= KC) return;
    const float4* row = (const float4*)(emb + (size_t)k * DIM);
    float s = 0.f;
    #pragma unroll 4
    for (int i = 0; i < DIM / 4; ++i) {
        float4 v = row[i];
        s += v.x * v.x + v.y * v.y + v.z * v.z + v.w * v.w;
    }
    enorm[k] = s;
}

__global__ __launch_bounds__(256) void argmin_kernel(const float* __restrict__ lat,
                                                     const float* __restrict__ emb,
                                                     const float* __restrict__ enorm,
                                                     int* __restrict__ inds,
                                                     int* __restrict__ hist) {
    __shared__ float As[DSTEP][PAD_M];
    __shared__ float Bs[DSTEP][PAD_M];
    __shared__ float rbest[BM][17];
    __shared__ int   ridx[BM][17];

    const int tid = threadIdx.x;
    const int tx = tid & 15;
    const int ty = tid >> 4;
    const int row0 = blockIdx.x * BM;
    const int lm  = tid >> 2;
    const int ld0 = (tid & 3) * 8;

    float best[4];
    int bidx[4];
    #pragma unroll
    for (int i = 0; i < 4; ++i) { best[i] = INFINITY; bidx[i] = 0; }

    for (int ct = 0; ct < KC / BN; ++ct) {
        float acc[4][4];
        #pragma unroll
        for (int i = 0; i < 4; ++i)
            #pragma unroll
            for (int j = 0; j < 4; ++j) acc[i][j] = 0.f;

        for (int dc = 0; dc < DIM; dc += DSTEP) {
            const float* ap = lat + (size_t)(row0 + lm) * DIM + dc + ld0;
            float4 a0 = *(const float4*)ap;
            float4 a1 = *(const float4*)(ap + 4);
            As[ld0 + 0][lm] = a0.x; As[ld0 + 1][lm] = a0.y;
            As[ld0 + 2][lm] = a0.z; As[ld0 + 3][lm] = a0.w;
            As[ld0 + 4][lm] = a1.x; As[ld0 + 5][lm] = a1.y;
            As[ld0 + 6][lm] = a1.z; As[ld0 + 7][lm] = a1.w;
            const float* bp = emb + (size_t)(ct * BN + lm) * DIM + dc + ld0;
            float4 b0 = *(const float4*)bp;
            float4 b1 = *(const float4*)(bp + 4);
            Bs[ld0 + 0][lm] = b0.x; Bs[ld0 + 1][lm] = b0.y;
            Bs[ld0 + 2][lm] = b0.z; Bs[ld0 + 3][lm] = b0.w;
            Bs[ld0 + 4][lm] = b1.x; Bs[ld0 + 5][lm] = b1.y;
            Bs[ld0 + 6][lm] = b1.z; Bs[ld0 + 7][lm] = b1.w;
            __syncthreads();
            #pragma unroll
            for (int d = 0; d < DSTEP; ++d) {
                float4 av = *(const float4*)&As[d][ty * 4];
                float4 bv = *(const float4*)&Bs[d][tx * 4];
                float a[4] = {av.x, av.y, av.z, av.w};
                float b[4] = {bv.x, bv.y, bv.z, bv.w};
                #pragma unroll
                for (int i = 0; i < 4; ++i)
                    #pragma unroll
                    for (int j = 0; j < 4; ++j)
                        acc[i][j] = fmaf(a[i], b[j], acc[i][j]);
            }
            __syncthreads();
        }
        #pragma unroll
        for (int j = 0; j < 4; ++j) {
            int n = ct * BN + tx * 4 + j;
            float en = enorm[n];
            #pragma unroll
            for (int i = 0; i < 4; ++i) {
                float dist = fmaf(-2.f, acc[i][j], en);
                if (dist < best[i]) { best[i] = dist; bidx[i] = n; }
            }
        }
    }
    #pragma unroll
    for (int i = 0; i < 4; ++i) {
        rbest[ty * 4 + i][tx] = best[i];
        ridx [ty * 4 + i][tx] = bidx[i];
    }
    __syncthreads();
    if (tid < BM) {
        float g1 = INFINITY;
        int i1 = 0x7fffffff;
        for (int t = 0; t < 16; ++t) {
            float d = rbest[tid][t];
            int   ix = ridx[tid][t];
            if (d < g1 || (d == g1 && ix < i1)) { g1 = d; i1 = ix; }
        }
        inds[row0 + tid] = i1;
        atomicAdd(&hist[i1], 1);
    }
}

__global__ __launch_bounds__(256) void gather_kernel(const float* __restrict__ lat,
                                                     const float* __restrict__ emb,
                                                     const int* __restrict__ inds,
                                                     float* __restrict__ out,
                                                     double* __restrict__ partials) {
    __shared__ double wsum[4];
    const int tid = threadIdx.x;
    double acc = 0.0;
    const int nvec = N_ROWS * DIM / 4;
    for (int idx = blockIdx.x * blockDim.x + tid; idx < nvec; idx += gridDim.x * blockDim.x) {
        int row = idx >> 6;
        int dv = idx & 63;
        int k = inds[row];
        float4 xv = ((const float4*)lat)[idx];
        float4 qv = ((const float4*)(emb + (size_t)k * DIM))[dv];
        float d0 = qv.x - xv.x, d1 = qv.y - xv.y, d2 = qv.z - xv.z, d3 = qv.w - xv.w;
        float4 o;
        o.x = xv.x + d0; o.y = xv.y + d1; o.z = xv.z + d2; o.w = xv.w + d3;
        ((float4*)out)[idx] = o;
        acc += (double)d0 * d0 + (double)d1 * d1 + (double)d2 * d2 + (double)d3 * d3;
    }
    #pragma unroll
    for (int off = 32; off >= 1; off >>= 1) acc += __shfl_xor(acc, off);
    if ((tid & 63) == 0) wsum[tid >> 6] = acc;
    __syncthreads();
    if (tid == 0) partials[blockIdx.x] = wsum[0] + wsum[1] + wsum[2] + wsum[3];
}

extern "C" void kernel_launch(void* const* d_in, const int* in_sizes, int n_in,
                              void* d_out, int out_size, void* d_ws, size_t ws_size,
                              hipStream_t stream) {
    const float* lat = (const float*)d_in[0];
    const float* emb = (const float*)d_in[1];
    float* out = (float*)d_out;

    char* ws = (char*)d_ws;
    int*    hist     = (int*)(ws);                    // 4 KB
    float*  enorm    = (float*)(ws + 4096);           // 4 KB
    int*    inds     = (int*)(ws + 8192);             // 128 KB
    double* partials = (double*)(ws + 139264);        // 16 KB
    u16*    eh       = (u16*)(ws + 155648);           // 512 KB
    const size_t WS_NEED = 155648 + 524288;

    if (ws_size >= WS_NEED) {
        split_e_kernel<<<KC / 4, 256, 0, stream>>>(emb, eh, enorm, hist);
        fused_argmin_kernel<<<N_ROWS / 128, 512, 0, stream>>>(lat, emb, eh, enorm,
                                                              inds, hist, partials, out);
        finalize_kernel<<<1, 256, 0, stream>>>(hist, partials, N_ROWS / 128,
                                               out + (size_t)N_ROWS * DIM);
    } else {
        hipMemsetAsync(hist, 0, KC * sizeof(int), stream);
        enorm_kernel<<<KC / 256, 256, 0, stream>>>(emb, enorm);
        argmin_kernel<<<N_ROWS / BM, 256, 0, stream>>>(lat, emb, enorm, inds, hist);
        gather_kernel<<<2048, 256, 0, stream>>>(lat, emb, inds, out, partials);
        finalize_kernel<<<1, 256, 0, stream>>>(hist, partials, 2048,
                                               out + (size_t)N_ROWS * DIM);
    }
}

// Round 13
// 55.678 us; speedup vs baseline: 1.6452x; 1.0900x over previous
//
#include <hip/hip_runtime.h>
#include <math.h>

#define N_ROWS 32768
#define DIM    256
#define KC     1024
#define BM     64
#define BN     64
#define DSTEP  32
#define PAD_M  68

typedef unsigned short u16;
typedef __attribute__((ext_vector_type(8))) short short8;
typedef __attribute__((ext_vector_type(4))) float f32x4;

__device__ __forceinline__ u16 bf16_rne(float f) {
    unsigned u = __float_as_uint(f);
    return (u16)((u + 0x7fffu + ((u >> 16) & 1u)) >> 16);
}

// ---------------- split codebook f32 -> bf16, fused row norms + hist zero ----------
__global__ __launch_bounds__(256) void split_e_kernel(const float* __restrict__ emb,
                                                      u16* __restrict__ hi,
                                                      float* __restrict__ enorm,
                                                      int* __restrict__ hist) {
    if (blockIdx.x < 4) hist[blockIdx.x * 256 + threadIdx.x] = 0;
    const int lane = threadIdx.x & 63;
    const int row  = blockIdx.x * 4 + (threadIdx.x >> 6);
    float4 v = ((const float4*)(emb + (size_t)row * DIM))[lane];
    ushort4 hv;
    hv.x = bf16_rne(v.x); hv.y = bf16_rne(v.y);
    hv.z = bf16_rne(v.z); hv.w = bf16_rne(v.w);
    ((ushort4*)(hi + (size_t)row * DIM))[lane] = hv;
    float ss = v.x * v.x + v.y * v.y + v.z * v.z + v.w * v.w;
    #pragma unroll
    for (int off = 32; off >= 1; off >>= 1) ss += __shfl_xor(ss, off);
    if (lane == 0) enorm[row] = ss;
}

// ---------------- fused argmin: A global->registers (no LDS), B LDS double-buffer ---
// Block: 256 thr / 4 waves = 2 row-groups x 2 col-groups; 64 rows x 1024 cols.
// Grid 512 -> 2 INDEPENDENT blocks/CU (no shared barriers -> stalls overlap).
// r8-r12 lesson: any in-loop A ds_read makes the kernel LDS-throughput-bound
// (~32 b128/wave/chunk vs 155 cyc MFMA) and the compiler won't register-carry
// LDS-sourced arrays across barrier loops. So A is loaded from GLOBAL into
// afr[2][8] (64 VGPR) and pinned with opaque asm (can't remat a global load
// cheaply; can't sink past the asm). K-loop reads ONLY B from LDS.
__global__ __launch_bounds__(256) void fused_argmin_kernel(
        const float* __restrict__ lat, const float* __restrict__ emb,
        const u16* __restrict__ eh, const float* __restrict__ enorm,
        int* __restrict__ inds, int* __restrict__ hist,
        double* __restrict__ partials, float* __restrict__ out) {
    __shared__ u16    Bbuf[2][64 * 256];  // 2 x 32 KB, swizzled (via src)
    __shared__ float  en_lds[KC];         // 4 KB
    __shared__ float  xn_lds[64];
    __shared__ float  ep_b[64][2];
    __shared__ int    ep_i[64][2];
    __shared__ double sred[64];

    const int tid  = threadIdx.x;
    const int l    = tid & 63;
    const int w    = tid >> 6;      // 0..3
    const int wrow = w >> 1;        // 0..1 : row group (32 rows each)
    const int wc   = w & 1;         // 0..1 : col group (32 cols per 64-col chunk)
    const int lcol = l & 15;
    const int kseg = l >> 4;        // 0..3
    const size_t row0 = (size_t)blockIdx.x * 64;

    // ---- stage enorm to LDS (keeps the K-loop free of stray vmem ops) ----
    #pragma unroll
    for (int i = 0; i < 4; ++i) en_lds[i * 256 + tid] = enorm[i * 256 + tid];

    // ---- A fragments: global f32 -> bf16 -> registers; fused row norms ----
    short8 afr[2][8];
    #pragma unroll
    for (int mf = 0; mf < 2; ++mf) {
        const int ra = wrow * 32 + mf * 16 + lcol;
        float ss = 0.f;
        #pragma unroll
        for (int ks = 0; ks < 8; ++ks) {
            const float* ap = lat + (row0 + ra) * 256 + ks * 32 + kseg * 8;
            float4 a0 = *(const float4*)ap;
            float4 a1 = *(const float4*)(ap + 4);
            short8 d;
            d[0] = (short)bf16_rne(a0.x); d[1] = (short)bf16_rne(a0.y);
            d[2] = (short)bf16_rne(a0.z); d[3] = (short)bf16_rne(a0.w);
            d[4] = (short)bf16_rne(a1.x); d[5] = (short)bf16_rne(a1.y);
            d[6] = (short)bf16_rne(a1.z); d[7] = (short)bf16_rne(a1.w);
            afr[mf][ks] = d;
            ss += a0.x * a0.x + a0.y * a0.y + a0.z * a0.z + a0.w * a0.w
                + a1.x * a1.x + a1.y * a1.y + a1.z * a1.z + a1.w * a1.w;
        }
        // pin fragments: opaque asm redefinition -> no remat, no sinking into loop
        #pragma unroll
        for (int ks = 0; ks < 8; ++ks)
            asm volatile("" : "+v"(afr[mf][ks]));
        // row-norm: elements of row ra live in lanes l, l^16, l^32, l^48
        ss += __shfl_xor(ss, 16);
        ss += __shfl_xor(ss, 32);
        if (wc == 0 && kseg == 0) xn_lds[wrow * 32 + mf * 16 + lcol] = ss;
    }

    // ---- issue B chunk 0 (pre-swizzled global source, linear LDS dest) ----
    #pragma unroll
    for (int i = 0; i < 8; ++i) {
        const int p = i * 256 + tid;     // 0..2047 = 64 rows x 32 chunks
        const int row = p >> 5;
        const int chp = p & 31;
        const u16* gb = eh + (size_t)row * 256 + (chp ^ (row & 7)) * 8;
        __builtin_amdgcn_global_load_lds(
            (const __attribute__((address_space(1))) void*)gb,
            (__attribute__((address_space(3))) void*)&Bbuf[0][p * 8], 16, 0, 0);
    }
    __syncthreads();   // staging barrier: drains A loads, en stage, chunk-0 loads

    float best[2][4];
    int   bidx[2][4];
    #pragma unroll
    for (int mf = 0; mf < 2; ++mf)
        #pragma unroll
        for (int r = 0; r < 4; ++r) { best[mf][r] = INFINITY; bidx[mf][r] = 0; }

    const int rb0 = wc * 32 + lcol;      // nf = 0 column (within 64-col chunk)
    const int rb1 = rb0 + 16;            // nf = 1
    for (int c = 0; c < 16; ++c) {
        if (c < 15) {   // prefetch next chunk; counted wait keeps it in flight
            #pragma unroll
            for (int i = 0; i < 8; ++i) {
                const int p = i * 256 + tid;
                const int row = p >> 5;
                const int chp = p & 31;
                const u16* gb = eh + (size_t)((c + 1) * 64 + row) * 256
                                   + (chp ^ (row & 7)) * 8;
                __builtin_amdgcn_global_load_lds(
                    (const __attribute__((address_space(1))) void*)gb,
                    (__attribute__((address_space(3))) void*)&Bbuf[(c + 1) & 1][p * 8],
                    16, 0, 0);
            }
            asm volatile("s_waitcnt vmcnt(8)" ::: "memory");  // chunk-c landed; c+1 in flight
        } else {
            asm volatile("s_waitcnt vmcnt(0)" ::: "memory");
        }
        __builtin_amdgcn_sched_barrier(0);
        __builtin_amdgcn_s_barrier();
        __builtin_amdgcn_sched_barrier(0);

        const u16* Bb = Bbuf[c & 1];
        const float en0 = en_lds[c * 64 + rb0];
        const float en1 = en_lds[c * 64 + rb1];

        f32x4 acc[2][2];
        #pragma unroll
        for (int mf = 0; mf < 2; ++mf)
            #pragma unroll
            for (int nf = 0; nf < 2; ++nf)
                acc[mf][nf] = (f32x4){0.f, 0.f, 0.f, 0.f};

        #pragma unroll
        for (int ks = 0; ks < 8; ++ks) {
            const int ch = ks * 4 + kseg;
            short8 b0 = *(const short8*)&Bb[(rb0 * 32 + (ch ^ (rb0 & 7))) * 8];
            short8 b1 = *(const short8*)&Bb[(rb1 * 32 + (ch ^ (rb1 & 7))) * 8];
            #pragma unroll
            for (int mf = 0; mf < 2; ++mf) {
                acc[mf][0] = __builtin_amdgcn_mfma_f32_16x16x32_bf16(
                    afr[mf][ks], b0, acc[mf][0], 0, 0, 0);
                acc[mf][1] = __builtin_amdgcn_mfma_f32_16x16x32_bf16(
                    afr[mf][ks], b1, acc[mf][1], 0, 0, 0);
            }
        }

        const int col0 = c * 64 + rb0;
        const int col1 = c * 64 + rb1;
        #pragma unroll
        for (int mf = 0; mf < 2; ++mf)
            #pragma unroll
            for (int r = 0; r < 4; ++r) {
                float d0 = fmaf(-2.f, acc[mf][0][r], en0);
                if (d0 < best[mf][r]) { best[mf][r] = d0; bidx[mf][r] = col0; }
                float d1 = fmaf(-2.f, acc[mf][1][r], en1);
                if (d1 < best[mf][r]) { best[mf][r] = d1; bidx[mf][r] = col1; }
            }
        __builtin_amdgcn_sched_barrier(0);
        __builtin_amdgcn_s_barrier();    // Bbuf[c&1] reads done -> c+2 may overwrite
        __builtin_amdgcn_sched_barrier(0);
    }

    // merge across the 16-lane col group (tie-break: smallest index)
    #pragma unroll
    for (int m = 1; m < 16; m <<= 1) {
        #pragma unroll
        for (int mf = 0; mf < 2; ++mf)
            #pragma unroll
            for (int r = 0; r < 4; ++r) {
                float b2 = __shfl_xor(best[mf][r], m);
                int   i2 = __shfl_xor(bidx[mf][r], m);
                if (b2 < best[mf][r] || (b2 == best[mf][r] && i2 < bidx[mf][r])) {
                    best[mf][r] = b2; bidx[mf][r] = i2;
                }
            }
    }
    if (lcol == 0) {
        #pragma unroll
        for (int mf = 0; mf < 2; ++mf)
            #pragma unroll
            for (int r = 0; r < 4; ++r) {
                const int rr = wrow * 32 + mf * 16 + kseg * 4 + r;
                ep_b[rr][wc] = best[mf][r];
                ep_i[rr][wc] = bidx[mf][r];
            }
    }
    __syncthreads();

    // final per-row merge; dist = ||x||^2 + best(enorm - 2 dot)
    if (tid < 64) {
        float b = ep_b[tid][0]; int bi = ep_i[tid][0];
        float b2 = ep_b[tid][1]; int i2 = ep_i[tid][1];
        if (b2 < b || (b2 == b && i2 < bi)) { b = b2; bi = i2; }
        inds[row0 + tid] = bi;
        atomicAdd(&hist[bi], 1);
        sred[tid] = (double)xn_lds[tid] + (double)b;
        ep_i[tid][0] = bi;
    }
    __syncthreads();

    // fused quantized-output write (emb rows L2-resident; coalesced stores)
    #pragma unroll
    for (int i = 0; i < 16; ++i) {
        const int vec = i * 256 + tid;        // 0..4095 = 64 rows x 64 float4
        const int row = vec >> 6;
        const int dv  = vec & 63;
        const int k   = ep_i[row][0];
        ((float4*)out)[(row0 + row) * 64 + dv] =
            ((const float4*)emb)[(size_t)k * 64 + dv];
    }

    for (int st = 32; st >= 1; st >>= 1) {
        if (tid < st) sred[tid] += sred[tid + st];
        __syncthreads();
    }
    if (tid == 0) partials[blockIdx.x] = sred[0];
}

// ---------------- finalize: vq_loss + perplexity ----------------
__global__ __launch_bounds__(256) void finalize_kernel(const int* __restrict__ hist,
                                                       const double* __restrict__ partials,
                                                       int np,
                                                       float* __restrict__ out_tail) {
    __shared__ double sh[256];
    const int tid = threadIdx.x;
    double s = 0.0;
    for (int i = tid; i < np; i += 256) s += partials[i];
    sh[tid] = s; __syncthreads();
    for (int st = 128; st > 0; st >>= 1) {
        if (tid < st) sh[tid] += sh[tid + st];
        __syncthreads();
    }
    double sumsq = sh[0];
    __syncthreads();
    double e = 0.0;
    for (int k = tid; k < KC; k += 256) {
        double p = (double)hist[k] / (double)N_ROWS;
        e += p * log(p + 1e-10);
    }
    sh[tid] = e; __syncthreads();
    for (int st = 128; st > 0; st >>= 1) {
        if (tid < st) sh[tid] += sh[tid + st];
        __syncthreads();
    }
    if (tid == 0) {
        double mse = sumsq / (double)((size_t)N_ROWS * DIM);
        out_tail[0] = (float)(1.25 * mse);
        out_tail[1] = (float)exp(-sh[0]);
    }
}

// ================= fallback path (ws too small) =================
__global__ __launch_bounds__(256) void enorm_kernel(const float* __restrict__ emb,
                                                    float* __restrict__ enorm) {
    int k = blockIdx.x * blockDim.x + threadIdx.x;
    if (k >= KC) return;
    const float4* row = (const float4*)(emb + (size_t)k * DIM);
    float s = 0.f;
    #pragma unroll 4
    for (int i = 0; i < DIM / 4; ++i) {
        float4 v = row[i];
        s += v.x * v.x + v.y * v.y + v.z * v.z + v.w * v.w;
    }
    enorm[k] = s;
}

__global__ __launch_bounds__(256) void argmin_kernel(const float* __restrict__ lat,
                                                     const float* __restrict__ emb,
                                                     const float* __restrict__ enorm,
                                                     int* __restrict__ inds,
                                                     int* __restrict__ hist) {
    __shared__ float As[DSTEP][PAD_M];
    __shared__ float Bs[DSTEP][PAD_M];
    __shared__ float rbest[BM][17];
    __shared__ int   ridx[BM][17];

    const int tid = threadIdx.x;
    const int tx = tid & 15;
    const int ty = tid >> 4;
    const int row0 = blockIdx.x * BM;
    const int lm  = tid >> 2;
    const int ld0 = (tid & 3) * 8;

    float best[4];
    int bidx[4];
    #pragma unroll
    for (int i = 0; i < 4; ++i) { best[i] = INFINITY; bidx[i] = 0; }

    for (int ct = 0; ct < KC / BN; ++ct) {
        float acc[4][4];
        #pragma unroll
        for (int i = 0; i < 4; ++i)
            #pragma unroll
            for (int j = 0; j < 4; ++j) acc[i][j] = 0.f;

        for (int dc = 0; dc < DIM; dc += DSTEP) {
            const float* ap = lat + (size_t)(row0 + lm) * DIM + dc + ld0;
            float4 a0 = *(const float4*)ap;
            float4 a1 = *(const float4*)(ap + 4);
            As[ld0 + 0][lm] = a0.x; As[ld0 + 1][lm] = a0.y;
            As[ld0 + 2][lm] = a0.z; As[ld0 + 3][lm] = a0.w;
            As[ld0 + 4][lm] = a1.x; As[ld0 + 5][lm] = a1.y;
            As[ld0 + 6][lm] = a1.z; As[ld0 + 7][lm] = a1.w;
            const float* bp = emb + (size_t)(ct * BN + lm) * DIM + dc + ld0;
            float4 b0 = *(const float4*)bp;
            float4 b1 = *(const float4*)(bp + 4);
            Bs[ld0 + 0][lm] = b0.x; Bs[ld0 + 1][lm] = b0.y;
            Bs[ld0 + 2][lm] = b0.z; Bs[ld0 + 3][lm] = b0.w;
            Bs[ld0 + 4][lm] = b1.x; Bs[ld0 + 5][lm] = b1.y;
            Bs[ld0 + 6][lm] = b1.z; Bs[ld0 + 7][lm] = b1.w;
            __syncthreads();
            #pragma unroll
            for (int d = 0; d < DSTEP; ++d) {
                float4 av = *(const float4*)&As[d][ty * 4];
                float4 bv = *(const float4*)&Bs[d][tx * 4];
                float a[4] = {av.x, av.y, av.z, av.w};
                float b[4] = {bv.x, bv.y, bv.z, bv.w};
                #pragma unroll
                for (int i = 0; i < 4; ++i)
                    #pragma unroll
                    for (int j = 0; j < 4; ++j)
                        acc[i][j] = fmaf(a[i], b[j], acc[i][j]);
            }
            __syncthreads();
        }
        #pragma unroll
        for (int j = 0; j < 4; ++j) {
            int n = ct * BN + tx * 4 + j;
            float en = enorm[n];
            #pragma unroll
            for (int i = 0; i < 4; ++i) {
                float dist = fmaf(-2.f, acc[i][j], en);
                if (dist < best[i]) { best[i] = dist; bidx[i] = n; }
            }
        }
    }
    #pragma unroll
    for (int i = 0; i < 4; ++i) {
        rbest[ty * 4 + i][tx] = best[i];
        ridx [ty * 4 + i][tx] = bidx[i];
    }
    __syncthreads();
    if (tid < BM) {
        float g1 = INFINITY;
        int i1 = 0x7fffffff;
        for (int t = 0; t < 16; ++t) {
            float d = rbest[tid][t];
            int   ix = ridx[tid][t];
            if (d < g1 || (d == g1 && ix < i1)) { g1 = d; i1 = ix; }
        }
        inds[row0 + tid] = i1;
        atomicAdd(&hist[i1], 1);
    }
}

__global__ __launch_bounds__(256) void gather_kernel(const float* __restrict__ lat,
                                                     const float* __restrict__ emb,
                                                     const int* __restrict__ inds,
                                                     float* __restrict__ out,
                                                     double* __restrict__ partials) {
    __shared__ double wsum[4];
    const int tid = threadIdx.x;
    double acc = 0.0;
    const int nvec = N_ROWS * DIM / 4;
    for (int idx = blockIdx.x * blockDim.x + tid; idx < nvec; idx += gridDim.x * blockDim.x) {
        int row = idx >> 6;
        int dv = idx & 63;
        int k = inds[row];
        float4 xv = ((const float4*)lat)[idx];
        float4 qv = ((const float4*)(emb + (size_t)k * DIM))[dv];
        float d0 = qv.x - xv.x, d1 = qv.y - xv.y, d2 = qv.z - xv.z, d3 = qv.w - xv.w;
        float4 o;
        o.x = xv.x + d0; o.y = xv.y + d1; o.z = xv.z + d2; o.w = xv.w + d3;
        ((float4*)out)[idx] = o;
        acc += (double)d0 * d0 + (double)d1 * d1 + (double)d2 * d2 + (double)d3 * d3;
    }
    #pragma unroll
    for (int off = 32; off >= 1; off >>= 1) acc += __shfl_xor(acc, off);
    if ((tid & 63) == 0) wsum[tid >> 6] = acc;
    __syncthreads();
    if (tid == 0) partials[blockIdx.x] = wsum[0] + wsum[1] + wsum[2] + wsum[3];
}

extern "C" void kernel_launch(void* const* d_in, const int* in_sizes, int n_in,
                              void* d_out, int out_size, void* d_ws, size_t ws_size,
                              hipStream_t stream) {
    const float* lat = (const float*)d_in[0];
    const float* emb = (const float*)d_in[1];
    float* out = (float*)d_out;

    char* ws = (char*)d_ws;
    int*    hist     = (int*)(ws);                    // 4 KB
    float*  enorm    = (float*)(ws + 4096);           // 4 KB
    int*    inds     = (int*)(ws + 8192);             // 128 KB
    double* partials = (double*)(ws + 139264);        // 16 KB
    u16*    eh       = (u16*)(ws + 155648);           // 512 KB
    const size_t WS_NEED = 155648 + 524288;

    if (ws_size >= WS_NEED) {
        split_e_kernel<<<KC / 4, 256, 0, stream>>>(emb, eh, enorm, hist);
        fused_argmin_kernel<<<N_ROWS / 64, 256, 0, stream>>>(lat, emb, eh, enorm,
                                                             inds, hist, partials, out);
        finalize_kernel<<<1, 256, 0, stream>>>(hist, partials, N_ROWS / 64,
                                               out + (size_t)N_ROWS * DIM);
    } else {
        hipMemsetAsync(hist, 0, KC * sizeof(int), stream);
        enorm_kernel<<<KC / 256, 256, 0, stream>>>(emb, enorm);
        argmin_kernel<<<N_ROWS / BM, 256, 0, stream>>>(lat, emb, enorm, inds, hist);
        gather_kernel<<<2048, 256, 0, stream>>>(lat, emb, inds, out, partials);
        finalize_kernel<<<1, 256, 0, stream>>>(hist, partials, 2048,
                                               out + (size_t)N_ROWS * DIM);
    }
}